// Round 1
// baseline (81.927 us; speedup 1.0000x reference)
//
#include <hip/hip_runtime.h>

// Problem: x (64, 1024, 1024) fp32.
// out[0..63]   = trace(x[b])                 = sum_i x[b,i,i]
// out[64..127] = trace(x[b] @ x[b])          = sum_{i,j} x[b,i,j]*x[b,j,i]
//
// Tile-pair decomposition over 64x64 tiles: for bi<bj the (bi,bj)+(bj,bi)
// contribution is 2 * sum A[r][c]*B[c][r]; for bi==bj it's the full tile
// self-sum (each element of x read from HBM exactly once -> 256 MiB total).

#define N 1024
#define NB 64
#define TILE 64
#define NT (N / TILE)            // 16
#define NPAIRS (NT * (NT + 1) / 2)  // 136

__global__ void zero_out_kernel(float* out) {
    int t = threadIdx.x;
    if (t < 2 * NB) out[t] = 0.0f;
}

__global__ __launch_bounds__(256) void trace_pair_kernel(const float* __restrict__ x,
                                                         float* __restrict__ out) {
    __shared__ float bt[TILE][TILE + 1];   // +1 pad: transpose reads 2-way (free)
    __shared__ float red[8];

    const int blk = blockIdx.x;
    const int b   = blk / NPAIRS;
    int p = blk % NPAIRS;

    // decode triangular pair index -> (bi, bj), bi <= bj
    int bi = 0;
    while (p >= NT - bi) { p -= NT - bi; ++bi; }
    const int bj = bi + p;

    const float* xb = x + (size_t)b * N * N;

    const int t   = threadIdx.x;
    const int tx4 = t & 15;   // float4 column within tile (0..15)
    const int ty  = t >> 4;   // row group (0..15)

    // Load B tile = x[b, bj*64.., bi*64..] into LDS, coalesced float4 rows.
    const float* Bbase = xb + (size_t)(bj * TILE) * N + bi * TILE;
    #pragma unroll
    for (int rr = 0; rr < 4; ++rr) {
        const int r = ty + rr * 16;
        const float4 v = *reinterpret_cast<const float4*>(Bbase + (size_t)r * N + tx4 * 4);
        bt[r][tx4 * 4 + 0] = v.x;
        bt[r][tx4 * 4 + 1] = v.y;
        bt[r][tx4 * 4 + 2] = v.z;
        bt[r][tx4 * 4 + 3] = v.w;
    }
    __syncthreads();

    float s  = 0.0f;
    float tr = 0.0f;

    if (bi != bj) {
        // Stream A tile = x[b, bi*64.., bj*64..] from global (coalesced),
        // multiply by transposed B from LDS.
        const float* Abase = xb + (size_t)(bi * TILE) * N + bj * TILE;
        #pragma unroll
        for (int rr = 0; rr < 4; ++rr) {
            const int r = ty + rr * 16;
            const int c = tx4 * 4;
            const float4 a = *reinterpret_cast<const float4*>(Abase + (size_t)r * N + tx4 * 4);
            s += a.x * bt[c + 0][r];
            s += a.y * bt[c + 1][r];
            s += a.z * bt[c + 2][r];
            s += a.w * bt[c + 3][r];
        }
        s *= 2.0f;   // (bi,bj) and (bj,bi) contribute equally
    } else {
        // Diagonal tile: both operands come from the single staged tile.
        #pragma unroll
        for (int rr = 0; rr < 4; ++rr) {
            const int r = ty + rr * 16;
            const int c = tx4 * 4;
            s += bt[r][c + 0] * bt[c + 0][r];
            s += bt[r][c + 1] * bt[c + 1][r];
            s += bt[r][c + 2] * bt[c + 2][r];
            s += bt[r][c + 3] * bt[c + 3][r];
        }
        if (t < TILE) tr = bt[t][t];   // trace contribution
    }

    // Block reduction: wave64 shuffle, then cross-wave via LDS.
    #pragma unroll
    for (int off = 32; off > 0; off >>= 1) {
        s  += __shfl_down(s,  off, 64);
        tr += __shfl_down(tr, off, 64);
    }
    const int wave = t >> 6;
    const int lane = t & 63;
    if (lane == 0) { red[wave] = s; red[4 + wave] = tr; }
    __syncthreads();
    if (t == 0) {
        const float stot = red[0] + red[1] + red[2] + red[3];
        atomicAdd(out + NB + b, stot);
        if (bi == bj) {
            const float trtot = red[4] + red[5] + red[6] + red[7];
            atomicAdd(out + b, trtot);
        }
    }
}

extern "C" void kernel_launch(void* const* d_in, const int* in_sizes, int n_in,
                              void* d_out, int out_size, void* d_ws, size_t ws_size,
                              hipStream_t stream) {
    (void)in_sizes; (void)n_in; (void)d_ws; (void)ws_size; (void)out_size;
    const float* x = (const float*)d_in[0];
    float* out = (float*)d_out;

    zero_out_kernel<<<1, 128, 0, stream>>>(out);
    trace_pair_kernel<<<NB * NPAIRS, 256, 0, stream>>>(x, out);
}

// Round 2
// 81.504 us; speedup vs baseline: 1.0052x; 1.0052x over previous
//
#include <hip/hip_runtime.h>

// x (64, 1024, 1024) fp32.
// out[0..63]   = trace(x[b])        = sum_i x[b,i,i]
// out[64..127] = trace(x[b] @ x[b]) = sum_{i,j} x[b,i,j]*x[b,j,i]
//
// 64x64 tile-pair decomposition: off-diagonal pair (bi,bj) contributes
// 2 * sum A[r][c]*B[c][r] (A = tile(bi,bj), B = tile(bj,bi)); diagonal tile
// contributes its full self-sum + the trace. Every element is fetched from
// HBM exactly once (256 MiB total).
//
// R2 change vs R1: register-stage BOTH tiles with 8 back-to-back independent
// global_load_dwordx4 per thread (single HBM round-trip per block), then one
// ds_write + barrier, then LDS/FMA only. R1 had two barrier-serialized memory
// phases per block and ran at ~3.5 TB/s; this targets ~6 TB/s.

#define N 1024
#define NB 64
#define TILE 64
#define NT (N / TILE)               // 16
#define NPAIRS (NT * (NT + 1) / 2)  // 136

__global__ void zero_out_kernel(float* out) {
    int t = threadIdx.x;
    if (t < 2 * NB) out[t] = 0.0f;
}

__global__ __launch_bounds__(256) void trace_pair_kernel(const float* __restrict__ x,
                                                         float* __restrict__ out) {
    __shared__ float bt[TILE][TILE + 1];   // +1 pad: transpose reads 2-way (free)
    __shared__ float red[8];

    const int blk = blockIdx.x;
    const int b   = blk / NPAIRS;
    int p = blk % NPAIRS;

    // decode triangular pair index -> (bi, bj), bi <= bj
    int bi = 0;
    while (p >= NT - bi) { p -= NT - bi; ++bi; }
    const int bj = bi + p;

    const float* xb = x + (size_t)b * N * N;

    const int t   = threadIdx.x;
    const int tx4 = t & 15;   // float4 column within tile (0..15)
    const int ty  = t >> 4;   // row group (0..15)

    const float* Bbase = xb + (size_t)(bj * TILE) * N + bi * TILE;  // tile (bj,bi)
    const float* Abase = xb + (size_t)(bi * TILE) * N + bj * TILE;  // tile (bi,bj)

    float4 av[4], bv[4];
    if (bi != bj) {
        // 8 independent loads, issued back-to-back: one HBM round-trip.
        #pragma unroll
        for (int rr = 0; rr < 4; ++rr) {
            const int r = ty + rr * 16;
            bv[rr] = *reinterpret_cast<const float4*>(Bbase + (size_t)r * N + tx4 * 4);
            av[rr] = *reinterpret_cast<const float4*>(Abase + (size_t)r * N + tx4 * 4);
        }
    } else {
        #pragma unroll
        for (int rr = 0; rr < 4; ++rr) {
            const int r = ty + rr * 16;
            bv[rr] = *reinterpret_cast<const float4*>(Bbase + (size_t)r * N + tx4 * 4);
            av[rr] = bv[rr];
        }
    }

    // Stage B in LDS (vector writes, contiguous).
    #pragma unroll
    for (int rr = 0; rr < 4; ++rr) {
        const int r = ty + rr * 16;
        bt[r][tx4 * 4 + 0] = bv[rr].x;
        bt[r][tx4 * 4 + 1] = bv[rr].y;
        bt[r][tx4 * 4 + 2] = bv[rr].z;
        bt[r][tx4 * 4 + 3] = bv[rr].w;
    }
    __syncthreads();

    float s  = 0.0f;
    float tr = 0.0f;

    #pragma unroll
    for (int rr = 0; rr < 4; ++rr) {
        const int r = ty + rr * 16;
        const int c = tx4 * 4;
        s += av[rr].x * bt[c + 0][r];
        s += av[rr].y * bt[c + 1][r];
        s += av[rr].z * bt[c + 2][r];
        s += av[rr].w * bt[c + 3][r];
    }
    if (bi != bj) {
        s *= 2.0f;   // (bi,bj) and (bj,bi) contribute equally
    } else {
        if (t < TILE) tr = bt[t][t];   // trace contribution
    }

    // Block reduction: wave64 shuffle, then cross-wave via LDS.
    #pragma unroll
    for (int off = 32; off > 0; off >>= 1) {
        s  += __shfl_down(s,  off, 64);
        tr += __shfl_down(tr, off, 64);
    }
    const int wave = t >> 6;
    const int lane = t & 63;
    if (lane == 0) { red[wave] = s; red[4 + wave] = tr; }
    __syncthreads();
    if (t == 0) {
        const float stot = red[0] + red[1] + red[2] + red[3];
        atomicAdd(out + NB + b, stot);
        if (bi == bj) {
            const float trtot = red[4] + red[5] + red[6] + red[7];
            atomicAdd(out + b, trtot);
        }
    }
}

extern "C" void kernel_launch(void* const* d_in, const int* in_sizes, int n_in,
                              void* d_out, int out_size, void* d_ws, size_t ws_size,
                              hipStream_t stream) {
    (void)in_sizes; (void)n_in; (void)d_ws; (void)ws_size; (void)out_size;
    const float* x = (const float*)d_in[0];
    float* out = (float*)d_out;

    zero_out_kernel<<<1, 128, 0, stream>>>(out);
    trace_pair_kernel<<<NB * NPAIRS, 256, 0, stream>>>(x, out);
}

// Round 3
// 49.646 us; speedup vs baseline: 1.6502x; 1.6417x over previous
//
#include <hip/hip_runtime.h>

// x (64, 1024, 1024) fp32.
// out[0..63]   = trace(x[b])        = sum_i x[b,i,i]
// out[64..127] = trace(x[b] @ x[b]) = sum_{i,j} x[b,i,j]*x[b,j,i]
//
// R3: 128x128 super-tile pairs (vs R2's 64x64) so every global read is a
// 512B contiguous segment (R2's 256B chunks ran at ~3.4 TB/s vs 6.9 TB/s
// fillBuffer => granularity theory). B tile (64KB) doesn't fit padded LDS,
// so it's staged in two 32KB phases split by interleaved row-PAIRS:
//   phase p stages rows c with ((c>>1)&1)==p  ->  row c lands at LDS slot
//   2*(c>>2)+(c&1). A thread owning A cols [4g,4g+4) then uses components
//   {x,y} in phase 0 (c=4g+j) and {z,w} in phase 1 (c=4g+2+j) -> all
//   threads busy in both phases. A (64KB) is held in 32 VGPRs throughout.
// Diagonal super-tiles stage B from the A registers (A==B): thread rb owns
// rows r = rb+16*rr, and ((r>>1)&1) == ((rb>>1)&1), so threads with
// ((rb>>1)&1)==p write all 8 rows in phase p. Total HBM = exactly 256 MiB.

#define N 1024
#define NB 64
#define BT 128
#define NT2 (N / BT)                   // 8
#define NPAIR2 (NT2 * (NT2 + 1) / 2)   // 36

__global__ void zero_out_kernel(float* out) {
    int t = threadIdx.x;
    if (t < 2 * NB) out[t] = 0.0f;
}

__global__ __launch_bounds__(512) void trace_pair_kernel(const float* __restrict__ x,
                                                         float* __restrict__ out) {
    __shared__ float bt[64][129];   // 32.25 KB; pad 129: transposed reads 2-way (free)
    __shared__ float red[16];

    const int blk = blockIdx.x;
    const int b   = blk / NPAIR2;
    int p = blk % NPAIR2;
    int bi = 0;
    while (p >= NT2 - bi) { p -= NT2 - bi; ++bi; }
    const int bj = bi + p;
    const bool diag = (bi == bj);

    const float* xb = x + (size_t)b * N * N;
    const int t  = threadIdx.x;
    const int g  = t & 31;    // float4 col within super-tile (0..31)
    const int rb = t >> 5;    // row base (0..15)

    const float* Arow0 = xb + (size_t)(BT * bi) * N + BT * bj + 4 * g;
    const float* Brow0 = xb + (size_t)(BT * bj) * N + BT * bi + 4 * g;

    // A super-tile: 8 rows/thread, 512B contiguous per wave-row.
    float4 av[8];
    #pragma unroll
    for (int rr = 0; rr < 8; ++rr) {
        av[rr] = *reinterpret_cast<const float4*>(Arow0 + (size_t)(rb + 16 * rr) * N);
    }

    // Phase-0 B rows (off-diag only): loader row lr covers c = 4*(lr>>1)+(lr&1).
    float4 bv[4];
    if (!diag) {
        #pragma unroll
        for (int q = 0; q < 4; ++q) {
            const int lr = rb + 16 * q;
            const int c  = 4 * (lr >> 1) + (lr & 1);
            bv[q] = *reinterpret_cast<const float4*>(Brow0 + (size_t)c * N);
        }
    }

    // Stage phase 0 (slot for row c is 2*(c>>2)+(c&1) == lr by construction).
    if (diag) {
        if (((rb >> 1) & 1) == 0) {
            #pragma unroll
            for (int rr = 0; rr < 8; ++rr) {
                const int r = rb + 16 * rr;
                const int slot = 2 * (r >> 2) + (r & 1);
                bt[slot][4 * g + 0] = av[rr].x;
                bt[slot][4 * g + 1] = av[rr].y;
                bt[slot][4 * g + 2] = av[rr].z;
                bt[slot][4 * g + 3] = av[rr].w;
            }
        }
    } else {
        #pragma unroll
        for (int q = 0; q < 4; ++q) {
            const int lr = rb + 16 * q;
            bt[lr][4 * g + 0] = bv[q].x;
            bt[lr][4 * g + 1] = bv[q].y;
            bt[lr][4 * g + 2] = bv[q].z;
            bt[lr][4 * g + 3] = bv[q].w;
        }
    }
    __syncthreads();

    // Prefetch phase-1 B rows (c = 4*(lr>>1)+2+(lr&1)) under phase-0 compute.
    if (!diag) {
        #pragma unroll
        for (int q = 0; q < 4; ++q) {
            const int lr = rb + 16 * q;
            const int c  = 4 * (lr >> 1) + 2 + (lr & 1);
            bv[q] = *reinterpret_cast<const float4*>(Brow0 + (size_t)c * N);
        }
    }

    float s  = 0.0f;
    float tr = 0.0f;

    // Compute phase 0: c = 4g+j, j in {0,1} -> av components x,y.
    #pragma unroll
    for (int rr = 0; rr < 8; ++rr) {
        const int r = rb + 16 * rr;
        s += av[rr].x * bt[2 * g + 0][r];
        s += av[rr].y * bt[2 * g + 1][r];
    }

    // Trace from registers (diag blocks own A==B; element (r,r) is held by
    // the thread with g == r>>2, rb == r&15; component = rb&3).
    if (diag) {
        const int cc = rb & 3;
        #pragma unroll
        for (int rr = 0; rr < 8; ++rr) {
            const int r = rb + 16 * rr;
            if ((r >> 2) == g) {
                tr += (cc == 0) ? av[rr].x : (cc == 1) ? av[rr].y
                    : (cc == 2) ? av[rr].z : av[rr].w;
            }
        }
    }

    __syncthreads();   // drain phase-0 reads before overwrite

    // Stage phase 1.
    if (diag) {
        if (((rb >> 1) & 1) == 1) {
            #pragma unroll
            for (int rr = 0; rr < 8; ++rr) {
                const int r = rb + 16 * rr;
                const int slot = 2 * (r >> 2) + (r & 1);
                bt[slot][4 * g + 0] = av[rr].x;
                bt[slot][4 * g + 1] = av[rr].y;
                bt[slot][4 * g + 2] = av[rr].z;
                bt[slot][4 * g + 3] = av[rr].w;
            }
        }
    } else {
        #pragma unroll
        for (int q = 0; q < 4; ++q) {
            const int lr = rb + 16 * q;
            bt[lr][4 * g + 0] = bv[q].x;
            bt[lr][4 * g + 1] = bv[q].y;
            bt[lr][4 * g + 2] = bv[q].z;
            bt[lr][4 * g + 3] = bv[q].w;
        }
    }
    __syncthreads();

    // Compute phase 1: c = 4g+2+j -> av components z,w. Same LDS slots.
    #pragma unroll
    for (int rr = 0; rr < 8; ++rr) {
        const int r = rb + 16 * rr;
        s += av[rr].z * bt[2 * g + 0][r];
        s += av[rr].w * bt[2 * g + 1][r];
    }

    if (!diag) s *= 2.0f;   // (BI,BJ) and (BJ,BI) contribute equally

    // Block reduction: wave64 shuffle, then cross-wave via LDS (8 waves).
    #pragma unroll
    for (int off = 32; off > 0; off >>= 1) {
        s  += __shfl_down(s,  off, 64);
        tr += __shfl_down(tr, off, 64);
    }
    const int wave = t >> 6;
    const int lane = t & 63;
    if (lane == 0) { red[wave] = s; red[8 + wave] = tr; }
    __syncthreads();
    if (t == 0) {
        float st = 0.0f, trt = 0.0f;
        #pragma unroll
        for (int w = 0; w < 8; ++w) { st += red[w]; trt += red[8 + w]; }
        atomicAdd(out + NB + b, st);
        if (diag) atomicAdd(out + b, trt);
    }
}

extern "C" void kernel_launch(void* const* d_in, const int* in_sizes, int n_in,
                              void* d_out, int out_size, void* d_ws, size_t ws_size,
                              hipStream_t stream) {
    (void)in_sizes; (void)n_in; (void)d_ws; (void)ws_size; (void)out_size;
    const float* x = (const float*)d_in[0];
    float* out = (float*)d_out;

    zero_out_kernel<<<1, 128, 0, stream>>>(out);
    trace_pair_kernel<<<NB * NPAIR2, 512, 0, stream>>>(x, out);
}